// Round 4
// baseline (233.550 us; speedup 1.0000x reference)
//
#include <hip/hip_runtime.h>
#include <hip/hip_bf16.h>
#include <stdint.h>

typedef unsigned int u32;
typedef unsigned short u16;
typedef unsigned char u8;
typedef __bf16 bf16x8 __attribute__((ext_vector_type(8)));
typedef float f32x4 __attribute__((ext_vector_type(4)));

#define NB 65536
#define NBLK 1280                    // 256 buckets padded to 64 rows: max 81664 rows
#define PERM_TOT (NBLK * 64)
#define INVR 0xFFFFFFFFu
#define BLK_DEAD 0xFFFFu

// LDS layout (bytes) — activations in MFMA A-fragment tile layout:
// region[mt][kt] 16x32 tile = 1KB, addr = (mt*KT+kt)*1024 + lane*16.
// All inner-loop ds_read_b128 are conflict-free and 16B-aligned.
#define O_ROWS 0
#define O_XJ   256                   // 4 tiles  (KT=1)  = 4 KB
#define O_P    (O_XJ + 4096)         // 16 tiles (KT=4)  = 16 KB
#define O_H    (O_P + 16384)         // 32 tiles (KT=8)  = 32 KB
#define O_RED  O_P                   // node3 partials alias P (16 KB exactly)
#define SM_BYTES (O_H + 32768)       // 53,504 -> 3 blocks/CU

// packed-weight tile starts (512 elems = 1KB per 32x16 tile)
// order: W0_0, W0_1, W1_pre, W1_0, W1_1, W2_pre, W2_0, W2_1, W3_pre, W3_0, W3_1
__device__ __host__ constexpr int TS(int m) {
  constexpr int t[12] = {0, 64, 320, 384, 1152, 1408, 1472, 2240, 2496, 2560, 3328, 3360};
  return t[m];
}

__device__ __forceinline__ u16 f2bf(float f) {
  u32 u = __builtin_bit_cast(u32, f);
  u32 r = (u + 0x7FFFu + ((u >> 16) & 1u)) >> 16;   // RNE
  return (u16)r;
}
__device__ __forceinline__ float relu_f(float x) { return x > 0.f ? x : 0.f; }
__device__ __forceinline__ f32x4 mfma16(bf16x8 a, bf16x8 b, f32x4 c) {
  return __builtin_amdgcn_mfma_f32_16x16x32_bf16(a, b, c, 0, 0, 0);
}

// Pack 4 accumulator values (rows quad*4+0..3, col l16 of 16x16 D tile) into two
// bf16-pair words via neighbor-lane exchange (verified rounds 1/3).
// w0 = (row m0, cols col,col+1), w1 = (row m0+1, cols col,col+1), col even.
__device__ __forceinline__ void mkpair(f32x4 acc, float bias, bool dorelu, int l16,
                                       u32& w0, u32& w1) {
  float v0 = acc[0] + bias, v1 = acc[1] + bias, v2 = acc[2] + bias, v3 = acc[3] + bias;
  if (dorelu) { v0 = relu_f(v0); v1 = relu_f(v1); v2 = relu_f(v2); v3 = relu_f(v3); }
  u32 a = (u32)f2bf(v0) | ((u32)f2bf(v1) << 16);
  u32 b = (u32)f2bf(v2) | ((u32)f2bf(v3) << 16);
  u32 ax = (u32)__shfl_xor((int)a, 1);
  u32 bx = (u32)__shfl_xor((int)b, 1);
  if ((l16 & 1) == 0) { w0 = (a & 0xffffu) | (ax << 16); w1 = (a >> 16) | (ax & 0xffff0000u); }
  else                { w0 = (bx & 0xffffu) | (b << 16); w1 = (bx >> 16) | (b & 0xffff0000u); }
}

// Store the (m0,col)/(m0+1,col) u32 pair into a fragment-layout region.
// element (row,col) -> tile(row>>4, col>>5), slot (row&15) + 16*((col&31)>>3),
// byte (col&7)*2. Row m0+1 (m0&15 <= 14) = slot+1 = +16 bytes.
__device__ __forceinline__ void frag_store_pair(char* base, int KT, int m0, int col,
                                                u32 w0, u32 w1) {
  char* d = base + (((m0 >> 4) * KT + (col >> 5)) << 10) +
            (((m0 & 15) + (((col & 31) >> 3) << 4)) << 4) + (col & 7) * 2;
  *(u32*)d = w0; *(u32*)(d + 16) = w1;
}

// ---------------- weight packing ----------------
// Tile (kt,nt): lane L holds B[kt*32 + (L>>4)*8 + j][nt*16 + (L&15)], j=0..7.
// Tile order [e][nt][kt].

struct PrepArgs {
  const float* src[11];
  int K[11], Nsrc[11];
  int tileStart[12];
};

__device__ __forceinline__ void prep_tile_dev(__bf16* __restrict__ pk, const PrepArgs& pa,
                                              int gt, int lane) {
  const int quad = lane >> 4, l16 = lane & 15;
  int m = 0;
  while (gt >= pa.tileStart[m + 1]) m++;
  const int loc = gt - pa.tileStart[m];
  const int K = pa.K[m], Ns = pa.Nsrc[m];
  const int Np = Ns < 16 ? 16 : Ns;
  const int KT = K >> 5, NT = Np >> 4;
  const int e = loc / (KT * NT), rem = loc % (KT * NT);
  const int nt = rem / KT, kt = rem % KT;
  const int k = kt * 32 + quad * 8, n = nt * 16 + l16;
  u32 hw[4];
  if (n < Ns) {
    const float* s = pa.src[m] + ((size_t)e * K + k) * Ns + n;
    u16 h[8];
#pragma unroll
    for (int j = 0; j < 8; j++) h[j] = f2bf(s[(size_t)j * Ns]);
    hw[0] = (u32)h[0] | ((u32)h[1] << 16);
    hw[1] = (u32)h[2] | ((u32)h[3] << 16);
    hw[2] = (u32)h[4] | ((u32)h[5] << 16);
    hw[3] = (u32)h[6] | ((u32)h[7] << 16);
  } else {
    hw[0] = hw[1] = hw[2] = hw[3] = 0u;
  }
  uint4 w; w.x = hw[0]; w.y = hw[1]; w.z = hw[2]; w.w = hw[3];
  *(uint4*)((char*)pk + (size_t)gt * 1024 + lane * 16) = w;
}

// ---------------- front-end kernel 1: route chunk + prep (overlapped) ----------------

__global__ __launch_bounds__(256) void k_front(const float* __restrict__ inp,
                                               u8* __restrict__ bkt,
                                               u32* __restrict__ cnt2,
                                               u32* __restrict__ rank,
                                               __bf16* __restrict__ pk, PrepArgs pa) {
  __shared__ u32 h[256];
  const int tid = threadIdx.x;
  if (blockIdx.x == 0) rank[tid] = 0u;
  h[tid] = 0u;
  __syncthreads();
  const int r = blockIdx.x * 256 + tid;
  const float4* oh = (const float4*)(inp + (size_t)r * 144 + 128);
  u32 b = 0;
#pragma unroll
  for (int j = 0; j < 4; j++) {
    float4 v = oh[j];
    u32 e = v.y > 0.5f ? 1u : (v.z > 0.5f ? 2u : (v.w > 0.5f ? 3u : 0u));
    b |= e << (2 * j);
  }
  bkt[r] = (u8)b;
  atomicAdd(&h[b], 1u);
  __syncthreads();
  cnt2[blockIdx.x * 256 + tid] = h[tid];
  // weight packing, grid-strided over the 840 tile-groups (4 tiles/group, 1/wave)
  for (int g4 = blockIdx.x; g4 < TS(11) / 4; g4 += 256)
    prep_tile_dev(pk, pa, g4 * 4 + (tid >> 6), tid & 63);
}

// ---------------- front-end kernel 2: redundant scan + scatter ----------------

__global__ __launch_bounds__(256) void k_place(const u8* __restrict__ bkt,
                                               const u32* __restrict__ cnt2,
                                               u32* __restrict__ rank,
                                               u16* __restrict__ blk2b,
                                               u32* __restrict__ perm) {
  __shared__ u32 s[256], base[256];
  const int tid = threadIdx.x;
  u32 c = 0;
#pragma unroll 8
  for (int j = 0; j < 256; j++) c += cnt2[j * 256 + tid];   // column sum: rows coalesced
  const u32 pad = (c + 63u) & ~63u;
  s[tid] = pad;
  __syncthreads();
  for (int d = 1; d < 256; d <<= 1) {
    u32 v = (tid >= d) ? s[tid - d] : 0u;
    __syncthreads();
    s[tid] += v;
    __syncthreads();
  }
  const u32 off = s[tid] - pad;        // exclusive padded offset of bucket `tid`
  const u32 total = s[255];
  __syncthreads();                     // s is reused below
  if (blockIdx.x == 0) {
    for (u32 i = off + c; i < off + pad; i++) perm[i] = INVR;
    // u16 blk2b: bucket 255 is a REAL bucket, 0xFFFF is the dead sentinel
    for (u32 blk = off >> 6; blk < (off + pad) >> 6; blk++) blk2b[blk] = (u16)tid;
    for (u32 blk = (total >> 6) + tid; blk < NBLK; blk += 256) blk2b[blk] = BLK_DEAD;
  }
  s[tid] = 0u;                         // reuse as this chunk's histogram
  __syncthreads();
  const int r = blockIdx.x * 256 + tid;
  const u32 b = bkt[r];
  const u32 lrk = atomicAdd(&s[b], 1u);
  __syncthreads();
  base[tid] = off + (s[tid] ? atomicAdd(&rank[tid], s[tid]) : 0u);  // chunk reservation
  __syncthreads();
  perm[base[b] + lrk] = (u32)r;
}

// ---------------- fused node-chain kernel (8 waves, N split 8-ways) ----------------

__device__ __forceinline__ void xj_load(const float* inp, u32 myrow, int tid, int node,
                                        float4& v0, float4& v1) {
  v0 = make_float4(0.f, 0.f, 0.f, 0.f); v1 = v0;
  if (tid < 256 && myrow != INVR) {
    const int c8 = (tid & 3) << 3;
    const float4* p = (const float4*)(inp + (size_t)myrow * 144 + node * 32 + c8);
    v0 = p[0]; v1 = p[1];
  }
}

// XJ fragment store: row r = tid>>2 holds cols c8..c8+7 (c8 = (tid&3)*8) -> exactly
// one lane-slot of tile (r>>4): lane = (r&15) + 16*(tid&3).  tid<256 only.
__device__ __forceinline__ void xj_store(char* sm, int tid, float4 v0, float4 v1) {
  if (tid >= 256) return;
  const int r = tid >> 2;
  uint4 w;
  w.x = (u32)f2bf(v0.x) | ((u32)f2bf(v0.y) << 16);
  w.y = (u32)f2bf(v0.z) | ((u32)f2bf(v0.w) << 16);
  w.z = (u32)f2bf(v1.x) | ((u32)f2bf(v1.y) << 16);
  w.w = (u32)f2bf(v1.z) | ((u32)f2bf(v1.w) << 16);
  *(uint4*)(sm + O_XJ + ((r >> 4) << 10) + ((((tid & 3) << 4) + (r & 15)) << 4)) = w;
}

// h = relu(xj @ Wp + bp) -> H  (also node0's first GEMM). Wave w covers cols [w*32, w*32+32).
__device__ __forceinline__ void pre_gemm(char* sm, u32 e, int wave, int lane,
                                         const __bf16* Wp, const float* bp) {
  const int l16 = lane & 15;
  const int wn0 = wave * 32;
  const int rsel = ((lane >> 4) << 2) + ((l16 & 1) ? 2 : 0);
  const int colp = l16 & ~1;
  float bias[2];
#pragma unroll
  for (int nt = 0; nt < 2; nt++) bias[nt] = bp[(size_t)e * 256 + wn0 + nt * 16 + l16];
  f32x4 acc[4][2];
#pragma unroll
  for (int i = 0; i < 4; i++) { acc[i][0] = (f32x4){0.f,0.f,0.f,0.f}; acc[i][1] = acc[i][0]; }
  bf16x8 a[4], b[2];
#pragma unroll
  for (int nt = 0; nt < 2; nt++)
    b[nt] = *(const bf16x8*)(Wp + (size_t)(e * 16 + (wn0 >> 4) + nt) * 512 + lane * 8);
#pragma unroll
  for (int mt = 0; mt < 4; mt++)
    a[mt] = *(const bf16x8*)(sm + O_XJ + (mt << 10) + lane * 16);
#pragma unroll
  for (int mt = 0; mt < 4; mt++)
#pragma unroll
    for (int nt = 0; nt < 2; nt++) acc[mt][nt] = mfma16(a[mt], b[nt], acc[mt][nt]);
#pragma unroll
  for (int nt = 0; nt < 2; nt++) {
    const int n = wn0 + nt * 16;
#pragma unroll
    for (int mt = 0; mt < 4; mt++) {
      u32 w0, w1;
      mkpair(acc[mt][nt], bias[nt], true, l16, w0, w1);
      frag_store_pair(sm + O_H, 8, mt * 16 + rsel, n + colp, w0, w1);
    }
  }
}

// h = relu(cat(P, H) @ Wm + bm) -> H   (K=384; kt 0..3 from P, 4..11 from H)
__device__ __forceinline__ void main_gemm(char* sm, u32 e, int wave, int lane,
                                          const __bf16* Wm, const float* bm) {
  const int l16 = lane & 15;
  const int wn0 = wave * 32;
  const int rsel = ((lane >> 4) << 2) + ((l16 & 1) ? 2 : 0);
  const int colp = l16 & ~1;
  float bias[2];
#pragma unroll
  for (int nt = 0; nt < 2; nt++) bias[nt] = bm[(size_t)e * 256 + wn0 + nt * 16 + l16];
  f32x4 acc[4][2];
#pragma unroll
  for (int i = 0; i < 4; i++) { acc[i][0] = (f32x4){0.f,0.f,0.f,0.f}; acc[i][1] = acc[i][0]; }
  const __bf16* bB = Wm + (size_t)(e * 16 + (wn0 >> 4)) * 12 * 512 + lane * 8;
  bf16x8 bb[2][2];
#pragma unroll
  for (int nt = 0; nt < 2; nt++) {
    bb[0][nt] = *(const bf16x8*)(bB + (size_t)(nt * 12 + 0) * 512);
    bb[1][nt] = *(const bf16x8*)(bB + (size_t)(nt * 12 + 1) * 512);
  }
#pragma unroll
  for (int kt = 0; kt < 12; kt++) {
    bf16x8 a[4];
#pragma unroll
    for (int mt = 0; mt < 4; mt++) {
      a[mt] = (kt < 4)
          ? *(const bf16x8*)(sm + O_P + ((mt * 4 + kt) << 10) + lane * 16)
          : *(const bf16x8*)(sm + O_H + ((mt * 8 + (kt - 4)) << 10) + lane * 16);
    }
#pragma unroll
    for (int mt = 0; mt < 4; mt++)
#pragma unroll
      for (int nt = 0; nt < 2; nt++) acc[mt][nt] = mfma16(a[mt], bb[kt & 1][nt], acc[mt][nt]);
    if (kt < 10) {
#pragma unroll
      for (int nt = 0; nt < 2; nt++)
        bb[kt & 1][nt] = *(const bf16x8*)(bB + (size_t)(nt * 12 + kt + 2) * 512);
    }
  }
  __syncthreads();   // all waves done reading P/H before H is overwritten
#pragma unroll
  for (int nt = 0; nt < 2; nt++) {
    const int n = wn0 + nt * 16;
#pragma unroll
    for (int mt = 0; mt < 4; mt++) {
      u32 w0, w1;
      mkpair(acc[mt][nt], bias[nt], true, l16, w0, w1);
      frag_store_pair(sm + O_H, 8, mt * 16 + rsel, n + colp, w0, w1);
    }
  }
  __syncthreads();
}

// xnext = relu(H @ Wo + bo) -> P  (nodes 0..2). Wave w covers cols [w*16, w*16+16).
__device__ __forceinline__ void out_gemm(char* sm, u32 e, int wave, int lane,
                                         const __bf16* Wo, const float* bo) {
  const int l16 = lane & 15;
  const int on0 = wave * 16;
  const int rsel = ((lane >> 4) << 2) + ((l16 & 1) ? 2 : 0);
  const int colp = l16 & ~1;
  const float bias0 = bo[(size_t)e * 128 + on0 + l16];
  f32x4 acc[4];
#pragma unroll
  for (int i = 0; i < 4; i++) acc[i] = (f32x4){0.f, 0.f, 0.f, 0.f};
  const __bf16* bB = Wo + (size_t)(e * 8 + (on0 >> 4)) * 8 * 512 + lane * 8;
  bf16x8 bb[2];
  bb[0] = *(const bf16x8*)(bB);
  bb[1] = *(const bf16x8*)(bB + 512);
#pragma unroll
  for (int kt = 0; kt < 8; kt++) {
    bf16x8 a[4];
#pragma unroll
    for (int mt = 0; mt < 4; mt++)
      a[mt] = *(const bf16x8*)(sm + O_H + ((mt * 8 + kt) << 10) + lane * 16);
#pragma unroll
    for (int mt = 0; mt < 4; mt++) acc[mt] = mfma16(a[mt], bb[kt & 1], acc[mt]);
    if (kt < 6) bb[kt & 1] = *(const bf16x8*)(bB + (size_t)(kt + 2) * 512);
  }
#pragma unroll
  for (int mt = 0; mt < 4; mt++) {
    u32 w0, w1;
    mkpair(acc[mt], bias0, true, l16, w0, w1);
    frag_store_pair(sm + O_P, 4, mt * 16 + rsel, on0 + colp, w0, w1);
  }
}

__global__ __launch_bounds__(512, 3) void fused_k(
    const float* __restrict__ inp, const u32* __restrict__ perm,
    const u16* __restrict__ blk2b, const __bf16* __restrict__ pk,
    const float* __restrict__ b0_0, const float* __restrict__ b0_1,
    const float* __restrict__ b1_p, const float* __restrict__ b1_0,
    const float* __restrict__ b1_1, const float* __restrict__ b2_p,
    const float* __restrict__ b2_0, const float* __restrict__ b2_1,
    const float* __restrict__ b3_p, const float* __restrict__ b3_0,
    const float* __restrict__ b3_1, float* __restrict__ dout) {
  const u32 b = blk2b[blockIdx.x];
  if (b == BLK_DEAD) return;
  __shared__ __align__(16) char sm[SM_BYTES];
  u32* rows = (u32*)sm;
  const int tid = threadIdx.x;
  const int wave = tid >> 6, lane = tid & 63, quad = lane >> 4, l16 = lane & 15;
  if (tid < 64) rows[tid] = perm[blockIdx.x * 64 + tid];
  const u32 e0 = b & 3u, e1 = (b >> 2) & 3u, e2 = (b >> 4) & 3u, e3 = (b >> 6) & 3u;
  __syncthreads();
  const u32 myrow = rows[(tid & 255) >> 2];

  float4 v0, v1;
  // ---- node 0 ----
  xj_load(inp, myrow, tid, 0, v0, v1);
  xj_store(sm, tid, v0, v1);
  __syncthreads();
  pre_gemm(sm, e0, wave, lane, pk + (size_t)TS(0) * 512, b0_0);   // h0 -> H
  __syncthreads();
  // ---- node 1 ----
  xj_load(inp, myrow, tid, 1, v0, v1);
  out_gemm(sm, e0, wave, lane, pk + (size_t)TS(1) * 512, b0_1);   // x -> P
  xj_store(sm, tid, v0, v1);
  __syncthreads();
  pre_gemm(sm, e1, wave, lane, pk + (size_t)TS(2) * 512, b1_p);
  __syncthreads();
  main_gemm(sm, e1, wave, lane, pk + (size_t)TS(3) * 512, b1_0);
  // ---- node 2 ----
  xj_load(inp, myrow, tid, 2, v0, v1);
  out_gemm(sm, e1, wave, lane, pk + (size_t)TS(4) * 512, b1_1);
  xj_store(sm, tid, v0, v1);
  __syncthreads();
  pre_gemm(sm, e2, wave, lane, pk + (size_t)TS(5) * 512, b2_p);
  __syncthreads();
  main_gemm(sm, e2, wave, lane, pk + (size_t)TS(6) * 512, b2_0);
  // ---- node 3 ----
  xj_load(inp, myrow, tid, 3, v0, v1);
  out_gemm(sm, e2, wave, lane, pk + (size_t)TS(7) * 512, b2_1);
  xj_store(sm, tid, v0, v1);
  __syncthreads();
  pre_gemm(sm, e3, wave, lane, pk + (size_t)TS(8) * 512, b3_p);
  __syncthreads();
  main_gemm(sm, e3, wave, lane, pk + (size_t)TS(9) * 512, b3_0);

  // out3: [64x256] @ W3_1[256x16pad] + b -> dout fp32 (K split across waves 0..3)
  {
    const __bf16* Wo3 = pk + (size_t)TS(10) * 512;
    if (wave < 4) {
      f32x4 acc3[4];
#pragma unroll
      for (int i = 0; i < 4; i++) acc3[i] = (f32x4){0.f, 0.f, 0.f, 0.f};
#pragma unroll
      for (int kk = 0; kk < 2; kk++) {
        const int kt = wave * 2 + kk;
        bf16x8 b3 = *(const bf16x8*)(Wo3 + (size_t)(e3 * 8 + kt) * 512 + lane * 8);
        bf16x8 a[4];
#pragma unroll
        for (int mt = 0; mt < 4; mt++)
          a[mt] = *(const bf16x8*)(sm + O_H + ((mt * 8 + kt) << 10) + lane * 16);
#pragma unroll
        for (int mt = 0; mt < 4; mt++) acc3[mt] = mfma16(a[mt], b3, acc3[mt]);
      }
#pragma unroll
      for (int mt = 0; mt < 4; mt++)
#pragma unroll
        for (int r = 0; r < 4; r++)
          *(float*)(sm + O_RED +
                    (((size_t)wave * 64 + mt * 16 + quad * 4 + r) * 16 + l16) * 4) = acc3[mt][r];
    }
    __syncthreads();
    if (tid < 256) {
      const int m = tid >> 2, c = (tid & 3) * 2;
      float s0 = 0.f, s1 = 0.f;
#pragma unroll
      for (int w = 0; w < 4; w++) {
        s0 += *(float*)(sm + O_RED + (((size_t)w * 64 + m) * 16 + c) * 4);
        s1 += *(float*)(sm + O_RED + (((size_t)w * 64 + m) * 16 + c + 1) * 4);
      }
      if (myrow != INVR) {
        float2 o;
        o.x = s0 + b3_1[(size_t)e3 * 8 + c];
        o.y = s1 + b3_1[(size_t)e3 * 8 + c + 1];
        *(float2*)(dout + (size_t)myrow * 8 + c) = o;
      }
    }
  }
}

// ---------------- host ----------------

extern "C" void kernel_launch(void* const* d_in, const int* in_sizes, int n_in,
                              void* d_out, int out_size, void* d_ws, size_t ws_size,
                              hipStream_t stream) {
  (void)in_sizes; (void)n_in; (void)out_size; (void)ws_size;
  const float* inp = (const float*)d_in[0];
  char* ws = (char*)d_ws;

  const size_t oBKT = 0;                                  // NB u8 = 64 KB
  const size_t oRANK = oBKT + NB;                         // 256 u32 = 1 KB
  const size_t oB2B = oRANK + 1024;                       // NBLK u16 = 2.5 KB
  const size_t oCNT2 = (oB2B + NBLK * 2 + 255) & ~(size_t)255;   // 256*256 u32 = 256 KB
  const size_t oPERM = oCNT2 + 256 * 256 * 4;             // PERM_TOT u32 = 320 KB
  const size_t oPK = (oPERM + (size_t)PERM_TOT * 4 + 255) & ~(size_t)255;

  u8* bkt = (u8*)(ws + oBKT);
  u32* rank = (u32*)(ws + oRANK);
  u16* blk2b = (u16*)(ws + oB2B);
  u32* cnt2 = (u32*)(ws + oCNT2);
  u32* perm = (u32*)(ws + oPERM);
  __bf16* pk = (__bf16*)(ws + oPK);

  PrepArgs pa;
  const int widx[11] = {1, 3, 5, 7, 9, 11, 13, 15, 17, 19, 21};
  const int Ks[11] = {32, 256, 32, 384, 256, 32, 384, 256, 32, 384, 256};
  const int Ns[11] = {256, 128, 256, 256, 128, 256, 256, 128, 256, 256, 8};
  for (int m = 0; m < 11; m++) {
    pa.src[m] = (const float*)d_in[widx[m]];
    pa.K[m] = Ks[m]; pa.Nsrc[m] = Ns[m]; pa.tileStart[m] = TS(m);
  }
  pa.tileStart[11] = TS(11);   // 3360 tiles

  hipLaunchKernelGGL(k_front, dim3(NB / 256), dim3(256), 0, stream,
                     inp, bkt, cnt2, rank, pk, pa);
  hipLaunchKernelGGL(k_place, dim3(NB / 256), dim3(256), 0, stream,
                     bkt, cnt2, rank, blk2b, perm);
  fused_k<<<NBLK, 512, 0, stream>>>(
      inp, perm, blk2b, pk,
      (const float*)d_in[2], (const float*)d_in[4],
      (const float*)d_in[6], (const float*)d_in[8], (const float*)d_in[10],
      (const float*)d_in[12], (const float*)d_in[14], (const float*)d_in[16],
      (const float*)d_in[18], (const float*)d_in[20], (const float*)d_in[22],
      (float*)d_out);
}

// Round 6
// 215.240 us; speedup vs baseline: 1.0851x; 1.0851x over previous
//
#include <hip/hip_runtime.h>
#include <hip/hip_bf16.h>
#include <stdint.h>

typedef unsigned int u32;
typedef unsigned short u16;
typedef unsigned char u8;
typedef __bf16 bf16x8 __attribute__((ext_vector_type(8)));
typedef float f32x4 __attribute__((ext_vector_type(4)));

#define NB 65536
#define NBLK 1280                    // 256 buckets padded to 64 rows: max 81664 rows
#define PERM_TOT (NBLK * 64)
#define INVR 0xFFFFFFFFu
#define BLK_DEAD 0xFFFFu

// LDS layout (bytes) — activations in MFMA A-fragment tile layout:
// region[mt][kt] 16x32 tile = 1KB, addr = (mt*KT+kt)*1024 + lane*16.
// All inner-loop ds_read_b128 are conflict-free and 16B-aligned.
#define O_ROWS 0
#define O_XJ   256                   // 4 tiles  (KT=1)  = 4 KB
#define O_P    (O_XJ + 4096)         // 16 tiles (KT=4)  = 16 KB
#define O_H    (O_P + 16384)         // 32 tiles (KT=8)  = 32 KB
#define O_RED  O_P                   // node3 partials alias P (16 KB exactly)
#define SM_BYTES (O_H + 32768)       // 53,504 -> 3 blocks/CU

// packed-weight tile starts (512 elems = 1KB per 32x16 tile)
// order: W0_0, W0_1, W1_pre, W1_0, W1_1, W2_pre, W2_0, W2_1, W3_pre, W3_0, W3_1
__device__ __host__ constexpr int TS(int m) {
  constexpr int t[12] = {0, 64, 320, 384, 1152, 1408, 1472, 2240, 2496, 2560, 3328, 3360};
  return t[m];
}

__device__ __forceinline__ u16 f2bf(float f) {
  u32 u = __builtin_bit_cast(u32, f);
  u32 r = (u + 0x7FFFu + ((u >> 16) & 1u)) >> 16;   // RNE
  return (u16)r;
}
// HW packed f32->bf16 RNE: dst = {bf16(lo), bf16(hi)<<16}. No builtin on gfx950;
// single VOP3P instruction replaces ~9 VALU ops of bit-math (learn_hip m240/T12).
__device__ __forceinline__ u32 cvtpk(float lo, float hi) {
  u32 r;
  asm("v_cvt_pk_bf16_f32 %0, %1, %2" : "=v"(r) : "v"(lo), "v"(hi));
  return r;
}
__device__ __forceinline__ float relu_f(float x) { return x > 0.f ? x : 0.f; }
__device__ __forceinline__ f32x4 mfma16(bf16x8 a, bf16x8 b, f32x4 c) {
  return __builtin_amdgcn_mfma_f32_16x16x32_bf16(a, b, c, 0, 0, 0);
}

// Pack 4 accumulator values (rows quad*4+0..3, col l16 of 16x16 D tile) into two
// bf16-pair words via neighbor-lane exchange (verified rounds 1/3).
// w0 = (row m0, cols col,col+1), w1 = (row m0+1, cols col,col+1), col even.
__device__ __forceinline__ void mkpair(f32x4 acc, float bias, bool dorelu, int l16,
                                       u32& w0, u32& w1) {
  float v0 = acc[0] + bias, v1 = acc[1] + bias, v2 = acc[2] + bias, v3 = acc[3] + bias;
  if (dorelu) { v0 = relu_f(v0); v1 = relu_f(v1); v2 = relu_f(v2); v3 = relu_f(v3); }
  u32 a = cvtpk(v0, v1);
  u32 b = cvtpk(v2, v3);
  u32 ax = (u32)__shfl_xor((int)a, 1);
  u32 bx = (u32)__shfl_xor((int)b, 1);
  if ((l16 & 1) == 0) { w0 = (a & 0xffffu) | (ax << 16); w1 = (a >> 16) | (ax & 0xffff0000u); }
  else                { w0 = (bx & 0xffffu) | (b << 16); w1 = (bx >> 16) | (b & 0xffff0000u); }
}

// Store the (m0,col)/(m0+1,col) u32 pair into a fragment-layout region.
// element (row,col) -> tile(row>>4, col>>5), slot (row&15) + 16*((col&31)>>3),
// byte (col&7)*2. Row m0+1 (m0&15 <= 14) = slot+1 = +16 bytes.
__device__ __forceinline__ void frag_store_pair(char* base, int KT, int m0, int col,
                                                u32 w0, u32 w1) {
  char* d = base + (((m0 >> 4) * KT + (col >> 5)) << 10) +
            (((m0 & 15) + (((col & 31) >> 3) << 4)) << 4) + (col & 7) * 2;
  *(u32*)d = w0; *(u32*)(d + 16) = w1;
}

// ---------------- weight packing ----------------
// Tile (kt,nt): lane L holds B[kt*32 + (L>>4)*8 + j][nt*16 + (L&15)], j=0..7.
// Tile order [e][nt][kt].

struct PrepArgs {
  const float* src[11];
  int K[11], Nsrc[11];
  int tileStart[12];
};

__device__ __forceinline__ void prep_tile_dev(__bf16* __restrict__ pk, const PrepArgs& pa,
                                              int gt, int lane) {
  const int quad = lane >> 4, l16 = lane & 15;
  int m = 0;
  while (gt >= pa.tileStart[m + 1]) m++;
  const int loc = gt - pa.tileStart[m];
  const int K = pa.K[m], Ns = pa.Nsrc[m];
  const int Np = Ns < 16 ? 16 : Ns;
  const int KT = K >> 5, NT = Np >> 4;
  const int e = loc / (KT * NT), rem = loc % (KT * NT);
  const int nt = rem / KT, kt = rem % KT;
  const int k = kt * 32 + quad * 8, n = nt * 16 + l16;
  u32 hw[4];
  if (n < Ns) {
    const float* s = pa.src[m] + ((size_t)e * K + k) * Ns + n;
    u16 h[8];
#pragma unroll
    for (int j = 0; j < 8; j++) h[j] = f2bf(s[(size_t)j * Ns]);
    hw[0] = (u32)h[0] | ((u32)h[1] << 16);
    hw[1] = (u32)h[2] | ((u32)h[3] << 16);
    hw[2] = (u32)h[4] | ((u32)h[5] << 16);
    hw[3] = (u32)h[6] | ((u32)h[7] << 16);
  } else {
    hw[0] = hw[1] = hw[2] = hw[3] = 0u;
  }
  uint4 w; w.x = hw[0]; w.y = hw[1]; w.z = hw[2]; w.w = hw[3];
  *(uint4*)((char*)pk + (size_t)gt * 1024 + lane * 16) = w;
}

// ---------------- front-end kernel 1: route chunk + prep (overlapped) ----------------

__global__ __launch_bounds__(256) void k_front(const float* __restrict__ inp,
                                               u8* __restrict__ bkt,
                                               u32* __restrict__ cnt2,
                                               u32* __restrict__ rank,
                                               __bf16* __restrict__ pk, PrepArgs pa) {
  __shared__ u32 h[256];
  const int tid = threadIdx.x;
  if (blockIdx.x == 0) rank[tid] = 0u;
  h[tid] = 0u;
  __syncthreads();
  const int r = blockIdx.x * 256 + tid;
  const float4* oh = (const float4*)(inp + (size_t)r * 144 + 128);
  u32 b = 0;
#pragma unroll
  for (int j = 0; j < 4; j++) {
    float4 v = oh[j];
    u32 e = v.y > 0.5f ? 1u : (v.z > 0.5f ? 2u : (v.w > 0.5f ? 3u : 0u));
    b |= e << (2 * j);
  }
  bkt[r] = (u8)b;
  atomicAdd(&h[b], 1u);
  __syncthreads();
  cnt2[blockIdx.x * 256 + tid] = h[tid];
  // weight packing, grid-strided over the 840 tile-groups (4 tiles/group, 1/wave)
  for (int g4 = blockIdx.x; g4 < TS(11) / 4; g4 += 256)
    prep_tile_dev(pk, pa, g4 * 4 + (tid >> 6), tid & 63);
}

// ---------------- front-end kernel 2: redundant scan + scatter ----------------

__global__ __launch_bounds__(256) void k_place(const u8* __restrict__ bkt,
                                               const u32* __restrict__ cnt2,
                                               u32* __restrict__ rank,
                                               u16* __restrict__ blk2b,
                                               u32* __restrict__ perm) {
  __shared__ u32 s[256], base[256];
  const int tid = threadIdx.x;
  u32 c = 0;
#pragma unroll 8
  for (int j = 0; j < 256; j++) c += cnt2[j * 256 + tid];   // column sum: rows coalesced
  const u32 pad = (c + 63u) & ~63u;
  s[tid] = pad;
  __syncthreads();
  for (int d = 1; d < 256; d <<= 1) {
    u32 v = (tid >= d) ? s[tid - d] : 0u;
    __syncthreads();
    s[tid] += v;
    __syncthreads();
  }
  const u32 off = s[tid] - pad;        // exclusive padded offset of bucket `tid`
  const u32 total = s[255];
  __syncthreads();                     // s is reused below
  if (blockIdx.x == 0) {
    for (u32 i = off + c; i < off + pad; i++) perm[i] = INVR;
    // u16 blk2b: bucket 255 is a REAL bucket, 0xFFFF is the dead sentinel
    for (u32 blk = off >> 6; blk < (off + pad) >> 6; blk++) blk2b[blk] = (u16)tid;
    for (u32 blk = (total >> 6) + tid; blk < NBLK; blk += 256) blk2b[blk] = BLK_DEAD;
  }
  s[tid] = 0u;                         // reuse as this chunk's histogram
  __syncthreads();
  const int r = blockIdx.x * 256 + tid;
  const u32 b = bkt[r];
  const u32 lrk = atomicAdd(&s[b], 1u);
  __syncthreads();
  base[tid] = off + (s[tid] ? atomicAdd(&rank[tid], s[tid]) : 0u);  // chunk reservation
  __syncthreads();
  perm[base[b] + lrk] = (u32)r;
}

// ---------------- fused node-chain kernel (8 waves, N split 8-ways) ----------------

__device__ __forceinline__ void xj_load(const float* inp, u32 myrow, int tid, int node,
                                        float4& v0, float4& v1) {
  v0 = make_float4(0.f, 0.f, 0.f, 0.f); v1 = v0;
  if (tid < 256 && myrow != INVR) {
    const int c8 = (tid & 3) << 3;
    const float4* p = (const float4*)(inp + (size_t)myrow * 144 + node * 32 + c8);
    v0 = p[0]; v1 = p[1];
  }
}

// XJ fragment store: row r = tid>>2 holds cols c8..c8+7 (c8 = (tid&3)*8) -> exactly
// one lane-slot of tile (r>>4): lane = (r&15) + 16*(tid&3).  tid<256 only.
__device__ __forceinline__ void xj_store(char* sm, int tid, float4 v0, float4 v1) {
  if (tid >= 256) return;
  const int r = tid >> 2;
  uint4 w;
  w.x = cvtpk(v0.x, v0.y);
  w.y = cvtpk(v0.z, v0.w);
  w.z = cvtpk(v1.x, v1.y);
  w.w = cvtpk(v1.z, v1.w);
  *(uint4*)(sm + O_XJ + ((r >> 4) << 10) + ((((tid & 3) << 4) + (r & 15)) << 4)) = w;
}

// h = relu(xj @ Wp + bp) -> H  (also node0's first GEMM). Wave w covers cols [w*32, w*32+32).
__device__ __forceinline__ void pre_gemm(char* sm, u32 e, int wave, int lane,
                                         const __bf16* Wp, const float* bp) {
  const int l16 = lane & 15;
  const int wn0 = wave * 32;
  const int rsel = ((lane >> 4) << 2) + ((l16 & 1) ? 2 : 0);
  const int colp = l16 & ~1;
  float bias[2];
#pragma unroll
  for (int nt = 0; nt < 2; nt++) bias[nt] = bp[(size_t)e * 256 + wn0 + nt * 16 + l16];
  f32x4 acc[4][2];
#pragma unroll
  for (int i = 0; i < 4; i++) { acc[i][0] = (f32x4){0.f,0.f,0.f,0.f}; acc[i][1] = acc[i][0]; }
  bf16x8 a[4], b[2];
#pragma unroll
  for (int nt = 0; nt < 2; nt++)
    b[nt] = *(const bf16x8*)(Wp + (size_t)(e * 16 + (wn0 >> 4) + nt) * 512 + lane * 8);
#pragma unroll
  for (int mt = 0; mt < 4; mt++)
    a[mt] = *(const bf16x8*)(sm + O_XJ + (mt << 10) + lane * 16);
#pragma unroll
  for (int mt = 0; mt < 4; mt++)
#pragma unroll
    for (int nt = 0; nt < 2; nt++) acc[mt][nt] = mfma16(a[mt], b[nt], acc[mt][nt]);
#pragma unroll
  for (int nt = 0; nt < 2; nt++) {
    const int n = wn0 + nt * 16;
#pragma unroll
    for (int mt = 0; mt < 4; mt++) {
      u32 w0, w1;
      mkpair(acc[mt][nt], bias[nt], true, l16, w0, w1);
      frag_store_pair(sm + O_H, 8, mt * 16 + rsel, n + colp, w0, w1);
    }
  }
}

// h = relu(cat(P, H) @ Wm + bm) -> H   (K=384; kt 0..3 from P, 4..11 from H)
__device__ __forceinline__ void main_gemm(char* sm, u32 e, int wave, int lane,
                                          const __bf16* Wm, const float* bm) {
  const int l16 = lane & 15;
  const int wn0 = wave * 32;
  const int rsel = ((lane >> 4) << 2) + ((l16 & 1) ? 2 : 0);
  const int colp = l16 & ~1;
  float bias[2];
#pragma unroll
  for (int nt = 0; nt < 2; nt++) bias[nt] = bm[(size_t)e * 256 + wn0 + nt * 16 + l16];
  f32x4 acc[4][2];
#pragma unroll
  for (int i = 0; i < 4; i++) { acc[i][0] = (f32x4){0.f,0.f,0.f,0.f}; acc[i][1] = acc[i][0]; }
  const __bf16* bB = Wm + (size_t)(e * 16 + (wn0 >> 4)) * 12 * 512 + lane * 8;
  bf16x8 bb[2][2];
#pragma unroll
  for (int nt = 0; nt < 2; nt++) {
    bb[0][nt] = *(const bf16x8*)(bB + (size_t)(nt * 12 + 0) * 512);
    bb[1][nt] = *(const bf16x8*)(bB + (size_t)(nt * 12 + 1) * 512);
  }
#pragma unroll
  for (int kt = 0; kt < 12; kt++) {
    bf16x8 a[4];
#pragma unroll
    for (int mt = 0; mt < 4; mt++) {
      a[mt] = (kt < 4)
          ? *(const bf16x8*)(sm + O_P + ((mt * 4 + kt) << 10) + lane * 16)
          : *(const bf16x8*)(sm + O_H + ((mt * 8 + (kt - 4)) << 10) + lane * 16);
    }
#pragma unroll
    for (int mt = 0; mt < 4; mt++)
#pragma unroll
      for (int nt = 0; nt < 2; nt++) acc[mt][nt] = mfma16(a[mt], bb[kt & 1][nt], acc[mt][nt]);
    if (kt < 10) {
#pragma unroll
      for (int nt = 0; nt < 2; nt++)
        bb[kt & 1][nt] = *(const bf16x8*)(bB + (size_t)(nt * 12 + kt + 2) * 512);
    }
  }
  __syncthreads();   // all waves done reading P/H before H is overwritten
#pragma unroll
  for (int nt = 0; nt < 2; nt++) {
    const int n = wn0 + nt * 16;
#pragma unroll
    for (int mt = 0; mt < 4; mt++) {
      u32 w0, w1;
      mkpair(acc[mt][nt], bias[nt], true, l16, w0, w1);
      frag_store_pair(sm + O_H, 8, mt * 16 + rsel, n + colp, w0, w1);
    }
  }
  __syncthreads();
}

// xnext = relu(H @ Wo + bo) -> P  (nodes 0..2). Wave w covers cols [w*16, w*16+16).
__device__ __forceinline__ void out_gemm(char* sm, u32 e, int wave, int lane,
                                         const __bf16* Wo, const float* bo) {
  const int l16 = lane & 15;
  const int on0 = wave * 16;
  const int rsel = ((lane >> 4) << 2) + ((l16 & 1) ? 2 : 0);
  const int colp = l16 & ~1;
  const float bias0 = bo[(size_t)e * 128 + on0 + l16];
  f32x4 acc[4];
#pragma unroll
  for (int i = 0; i < 4; i++) acc[i] = (f32x4){0.f, 0.f, 0.f, 0.f};
  const __bf16* bB = Wo + (size_t)(e * 8 + (on0 >> 4)) * 8 * 512 + lane * 8;
  bf16x8 bb[2];
  bb[0] = *(const bf16x8*)(bB);
  bb[1] = *(const bf16x8*)(bB + 512);
#pragma unroll
  for (int kt = 0; kt < 8; kt++) {
    bf16x8 a[4];
#pragma unroll
    for (int mt = 0; mt < 4; mt++)
      a[mt] = *(const bf16x8*)(sm + O_H + ((mt * 8 + kt) << 10) + lane * 16);
#pragma unroll
    for (int mt = 0; mt < 4; mt++) acc[mt] = mfma16(a[mt], bb[kt & 1], acc[mt]);
    if (kt < 6) bb[kt & 1] = *(const bf16x8*)(bB + (size_t)(kt + 2) * 512);
  }
#pragma unroll
  for (int mt = 0; mt < 4; mt++) {
    u32 w0, w1;
    mkpair(acc[mt], bias0, true, l16, w0, w1);
    frag_store_pair(sm + O_P, 4, mt * 16 + rsel, on0 + colp, w0, w1);
  }
}

__global__ __launch_bounds__(512, 6) void fused_k(
    const float* __restrict__ inp, const u32* __restrict__ perm,
    const u16* __restrict__ blk2b, const __bf16* __restrict__ pk,
    const float* __restrict__ b0_0, const float* __restrict__ b0_1,
    const float* __restrict__ b1_p, const float* __restrict__ b1_0,
    const float* __restrict__ b1_1, const float* __restrict__ b2_p,
    const float* __restrict__ b2_0, const float* __restrict__ b2_1,
    const float* __restrict__ b3_p, const float* __restrict__ b3_0,
    const float* __restrict__ b3_1, float* __restrict__ dout) {
  const u32 b = blk2b[blockIdx.x];
  if (b == BLK_DEAD) return;
  __shared__ __align__(16) char sm[SM_BYTES];
  u32* rows = (u32*)sm;
  const int tid = threadIdx.x;
  const int wave = tid >> 6, lane = tid & 63, quad = lane >> 4, l16 = lane & 15;
  if (tid < 64) rows[tid] = perm[blockIdx.x * 64 + tid];
  const u32 e0 = b & 3u, e1 = (b >> 2) & 3u, e2 = (b >> 4) & 3u, e3 = (b >> 6) & 3u;
  __syncthreads();
  const u32 myrow = rows[(tid & 255) >> 2];

  float4 v0, v1;
  // ---- node 0 ----
  xj_load(inp, myrow, tid, 0, v0, v1);
  xj_store(sm, tid, v0, v1);
  __syncthreads();
  pre_gemm(sm, e0, wave, lane, pk + (size_t)TS(0) * 512, b0_0);   // h0 -> H
  __syncthreads();
  // ---- node 1 ----
  xj_load(inp, myrow, tid, 1, v0, v1);
  out_gemm(sm, e0, wave, lane, pk + (size_t)TS(1) * 512, b0_1);   // x -> P
  xj_store(sm, tid, v0, v1);
  __syncthreads();
  pre_gemm(sm, e1, wave, lane, pk + (size_t)TS(2) * 512, b1_p);
  __syncthreads();
  main_gemm(sm, e1, wave, lane, pk + (size_t)TS(3) * 512, b1_0);
  // ---- node 2 ----
  xj_load(inp, myrow, tid, 2, v0, v1);
  out_gemm(sm, e1, wave, lane, pk + (size_t)TS(4) * 512, b1_1);
  xj_store(sm, tid, v0, v1);
  __syncthreads();
  pre_gemm(sm, e2, wave, lane, pk + (size_t)TS(5) * 512, b2_p);
  __syncthreads();
  main_gemm(sm, e2, wave, lane, pk + (size_t)TS(6) * 512, b2_0);
  // ---- node 3 ----
  xj_load(inp, myrow, tid, 3, v0, v1);
  out_gemm(sm, e2, wave, lane, pk + (size_t)TS(7) * 512, b2_1);
  xj_store(sm, tid, v0, v1);
  __syncthreads();
  pre_gemm(sm, e3, wave, lane, pk + (size_t)TS(8) * 512, b3_p);
  __syncthreads();
  main_gemm(sm, e3, wave, lane, pk + (size_t)TS(9) * 512, b3_0);

  // out3: [64x256] @ W3_1[256x16pad] + b -> dout fp32 (K split across waves 0..3)
  {
    const __bf16* Wo3 = pk + (size_t)TS(10) * 512;
    if (wave < 4) {
      f32x4 acc3[4];
#pragma unroll
      for (int i = 0; i < 4; i++) acc3[i] = (f32x4){0.f, 0.f, 0.f, 0.f};
#pragma unroll
      for (int kk = 0; kk < 2; kk++) {
        const int kt = wave * 2 + kk;
        bf16x8 b3 = *(const bf16x8*)(Wo3 + (size_t)(e3 * 8 + kt) * 512 + lane * 8);
        bf16x8 a[4];
#pragma unroll
        for (int mt = 0; mt < 4; mt++)
          a[mt] = *(const bf16x8*)(sm + O_H + ((mt * 8 + kt) << 10) + lane * 16);
#pragma unroll
        for (int mt = 0; mt < 4; mt++) acc3[mt] = mfma16(a[mt], b3, acc3[mt]);
      }
#pragma unroll
      for (int mt = 0; mt < 4; mt++)
#pragma unroll
        for (int r = 0; r < 4; r++)
          *(float*)(sm + O_RED +
                    (((size_t)wave * 64 + mt * 16 + quad * 4 + r) * 16 + l16) * 4) = acc3[mt][r];
    }
    __syncthreads();
    if (tid < 256) {
      const int m = tid >> 2, c = (tid & 3) * 2;
      float s0 = 0.f, s1 = 0.f;
#pragma unroll
      for (int w = 0; w < 4; w++) {
        s0 += *(float*)(sm + O_RED + (((size_t)w * 64 + m) * 16 + c) * 4);
        s1 += *(float*)(sm + O_RED + (((size_t)w * 64 + m) * 16 + c + 1) * 4);
      }
      if (myrow != INVR) {
        float2 o;
        o.x = s0 + b3_1[(size_t)e3 * 8 + c];
        o.y = s1 + b3_1[(size_t)e3 * 8 + c + 1];
        *(float2*)(dout + (size_t)myrow * 8 + c) = o;
      }
    }
  }
}

// ---------------- host ----------------

extern "C" void kernel_launch(void* const* d_in, const int* in_sizes, int n_in,
                              void* d_out, int out_size, void* d_ws, size_t ws_size,
                              hipStream_t stream) {
  (void)in_sizes; (void)n_in; (void)out_size; (void)ws_size;
  const float* inp = (const float*)d_in[0];
  char* ws = (char*)d_ws;

  const size_t oBKT = 0;                                  // NB u8 = 64 KB
  const size_t oRANK = oBKT + NB;                         // 256 u32 = 1 KB
  const size_t oB2B = oRANK + 1024;                       // NBLK u16 = 2.5 KB
  const size_t oCNT2 = (oB2B + NBLK * 2 + 255) & ~(size_t)255;   // 256*256 u32 = 256 KB
  const size_t oPERM = oCNT2 + 256 * 256 * 4;             // PERM_TOT u32 = 320 KB
  const size_t oPK = (oPERM + (size_t)PERM_TOT * 4 + 255) & ~(size_t)255;

  u8* bkt = (u8*)(ws + oBKT);
  u32* rank = (u32*)(ws + oRANK);
  u16* blk2b = (u16*)(ws + oB2B);
  u32* cnt2 = (u32*)(ws + oCNT2);
  u32* perm = (u32*)(ws + oPERM);
  __bf16* pk = (__bf16*)(ws + oPK);

  PrepArgs pa;
  const int widx[11] = {1, 3, 5, 7, 9, 11, 13, 15, 17, 19, 21};
  const int Ks[11] = {32, 256, 32, 384, 256, 32, 384, 256, 32, 384, 256};
  const int Ns[11] = {256, 128, 256, 256, 128, 256, 256, 128, 256, 256, 8};
  for (int m = 0; m < 11; m++) {
    pa.src[m] = (const float*)d_in[widx[m]];
    pa.K[m] = Ks[m]; pa.Nsrc[m] = Ns[m]; pa.tileStart[m] = TS(m);
  }
  pa.tileStart[11] = TS(11);   // 3360 tiles

  hipLaunchKernelGGL(k_front, dim3(NB / 256), dim3(256), 0, stream,
                     inp, bkt, cnt2, rank, pk, pa);
  hipLaunchKernelGGL(k_place, dim3(NB / 256), dim3(256), 0, stream,
                     bkt, cnt2, rank, blk2b, perm);
  fused_k<<<NBLK, 512, 0, stream>>>(
      inp, perm, blk2b, pk,
      (const float*)d_in[2], (const float*)d_in[4],
      (const float*)d_in[6], (const float*)d_in[8], (const float*)d_in[10],
      (const float*)d_in[12], (const float*)d_in[14], (const float*)d_in[16],
      (const float*)d_in[18], (const float*)d_in[20], (const float*)d_in[22],
      (float*)d_out);
}